// Round 1
// baseline (178.802 us; speedup 1.0000x reference)
//
#include <hip/hip_runtime.h>
#include <cstdint>

constexpr int BTOT = 1048576;
constexpr int LCLS = 81;
constexpr int GRP  = 9;
constexpr int ROWS = 128;               // rows per block
constexpr int NBLK = BTOT / ROWS;       // 8192
constexpr float FIX = 67108864.0f;      // 2^26 fixed-point scale for loss

__global__ __launch_bounds__(ROWS) void hl_main(
    const float* __restrict__ x, const int* __restrict__ tgt,
    float* __restrict__ out, unsigned long long* __restrict__ part)
{
    __shared__ float tile[ROWS * LCLS];     // 41,472 B
    const int tid = threadIdx.x;
    const int blk = blockIdx.x;

    // ---- stage: contiguous 128-row tile, coalesced float4 ----
    {
        const float4* g4 = reinterpret_cast<const float4*>(x + (size_t)blk * (ROWS * LCLS));
        float4* l4 = reinterpret_cast<float4*>(tile);
        const int n4 = ROWS * LCLS / 4;     // 2592
        for (int i = tid; i < n4; i += ROWS) l4[i] = g4[i];
    }
    __syncthreads();

    const int grow = blk * ROWS + tid;
    const float* xr = tile + tid * LCLS;    // stride 81 words: 2-way bank alias = free

    // ---- group sums of exp (no max-subtract: |x| <~ 6, safe in f32) ----
    float gs[GRP];
    #pragma unroll
    for (int g = 0; g < GRP; ++g) {
        float s = 0.0f;
        #pragma unroll
        for (int j = 0; j < GRP; ++j) s += expf(xr[g * GRP + j]);
        gs[g] = s;
    }
    float S = gs[0];
    #pragma unroll
    for (int g = 1; g < GRP; ++g) S += gs[g];

    const int t = tgt[grow];
    const int parent = t / GRP;

    // ---- group argmax with top-2 tracking (strict > keeps first index) ----
    float g1 = gs[0], g2 = -1e30f; int gi = 0;
    #pragma unroll
    for (int g = 1; g < GRP; ++g) {
        float v = gs[g];
        bool gt = v > g1;
        g2 = gt ? g1 : (v > g2 ? v : g2);
        g1 = gt ? v  : g1;
        gi = gt ? g  : gi;
    }

    // ---- within-group argmax with top-2 tracking ----
    const float* xg = xr + gi * GRP;
    float w1 = expf(xg[0]), w2 = -1e30f; int wi = 0;
    #pragma unroll
    for (int j = 1; j < GRP; ++j) {
        float v = expf(xg[j]);
        bool gt2 = v > w1;
        w2 = gt2 ? w1 : (v > w2 ? v : w2);
        w1 = gt2 ? v  : w1;
        wi = gt2 ? j  : wi;
    }

    // ---- rare f64 refinement for knife-edge argmaxes (~4e-4 of rows) ----
    if ((g1 - g2 < 1e-5f * g1) || (w1 - w2 < 1e-5f * w1)) {
        double dgs[GRP];
        #pragma unroll
        for (int g = 0; g < GRP; ++g) {
            double s = 0.0;
            #pragma unroll
            for (int j = 0; j < GRP; ++j) s += exp((double)xr[g * GRP + j]);
            dgs[g] = s;
        }
        double dg1 = dgs[0]; int dgi = 0;
        #pragma unroll
        for (int g = 1; g < GRP; ++g) { if (dgs[g] > dg1) { dg1 = dgs[g]; dgi = g; } }
        const float* xg2 = xr + dgi * GRP;
        double dw1 = exp((double)xg2[0]); int dwi = 0;
        #pragma unroll
        for (int j = 1; j < GRP; ++j) {
            double v = exp((double)xg2[j]);
            if (v > dw1) { dw1 = v; dwi = j; }
        }
        gi = dgi; wi = dwi;
    }

    const int pred = gi * GRP + wi;

    // ---- loss term (f32; threshold is ~2% so f32 precision is ample) ----
    float et = expf(xr[t]);
    float gpar = gs[0];
    #pragma unroll
    for (int g = 1; g < GRP; ++g) gpar = (parent == g) ? gs[g] : gpar;  // static-index select chain
    float win = 0.5f * (gpar / S) + 0.5f * (et / S);
    float nl = -logf(win);                           // >= 0
    unsigned long long lq = (unsigned long long)llrintf(nl * FIX);
    int dist = (pred == t) ? 0 : ((gi == parent) ? 1 : 2);

    out[1 + grow] = (float)pred;

    // ---- deterministic block reduction: fixed-point loss + int dist ----
    #pragma unroll
    for (int off = 32; off > 0; off >>= 1) {
        lq   += __shfl_down(lq, off);
        dist += __shfl_down(dist, off);
    }
    __shared__ unsigned long long redL[ROWS / 64];
    __shared__ unsigned long long redD[ROWS / 64];
    if ((tid & 63) == 0) { redL[tid >> 6] = lq; redD[tid >> 6] = (unsigned long long)(unsigned)dist; }
    __syncthreads();
    if (tid == 0) {
        unsigned long long a = redL[0], b = redD[0];
        #pragma unroll
        for (int w = 1; w < ROWS / 64; ++w) { a += redL[w]; b += redD[w]; }
        part[blk] = a;
        part[NBLK + blk] = b;
    }
}

__global__ __launch_bounds__(256) void hl_final(
    const unsigned long long* __restrict__ part, float* __restrict__ out)
{
    const int tid = threadIdx.x;
    unsigned long long a = 0, b = 0;
    for (int i = tid; i < NBLK; i += 256) { a += part[i]; b += part[NBLK + i]; }
    #pragma unroll
    for (int off = 32; off > 0; off >>= 1) { a += __shfl_down(a, off); b += __shfl_down(b, off); }
    __shared__ unsigned long long rA[4], rB[4];
    if ((tid & 63) == 0) { rA[tid >> 6] = a; rB[tid >> 6] = b; }
    __syncthreads();
    if (tid == 0) {
        unsigned long long ta = 0, tb = 0;
        #pragma unroll
        for (int w = 0; w < 4; ++w) { ta += rA[w]; tb += rB[w]; }
        double loss = ((double)ta / 67108864.0) / (double)BTOT;
        out[0] = (float)loss;                  // -mean(log(win))
        out[1 + BTOT] = (float)tb;             // total_dist
    }
}

extern "C" void kernel_launch(void* const* d_in, const int* in_sizes, int n_in,
                              void* d_out, int out_size, void* d_ws, size_t ws_size,
                              hipStream_t stream) {
    const float* outputs = (const float*)d_in[0];
    const int*   target  = (const int*)d_in[1];
    float* out = (float*)d_out;
    unsigned long long* part = (unsigned long long*)d_ws;   // needs 2*8192*8 = 131,072 B

    hl_main<<<NBLK, ROWS, 0, stream>>>(outputs, target, out, part);
    hl_final<<<1, 256, 0, stream>>>(part, out);
}